// Round 1
// baseline (298.547 us; speedup 1.0000x reference)
//
#include <hip/hip_runtime.h>
#include <math.h>

#define B_   32
#define D_   128
#define L_   512
#define NH_  8
#define DK_  16

// ---------------------------------------------------------------------------
// Kernel A: per (head n, batch b) block: QKV projection + column-softmax
// attention. heads written to ws as [b][128][L], already head-reversed so
// kernel B is a plain batched GEMM.
// ---------------------------------------------------------------------------
__global__ __launch_bounds__(256) void attn_fused(
    const float* __restrict__ x,    // [B][D][L]
    const float* __restrict__ Wq,   // [NH][B][DK][D]
    const float* __restrict__ Wk,
    const float* __restrict__ Wv,
    float* __restrict__ heads)      // [B][NH*DK][L]
{
    __shared__ __attribute__((aligned(16))) float Qs[DK_][L_];
    __shared__ __attribute__((aligned(16))) float Ks[DK_][L_];
    __shared__ __attribute__((aligned(16))) float Vs[DK_][L_];
    __shared__ __attribute__((aligned(16))) float Ws[DK_][D_];

    const int nb = blockIdx.x;
    const int n  = nb >> 5;        // head
    const int b  = nb & 31;        // batch
    const int t  = threadIdx.x;

    const float* xb = x + (size_t)b * D_ * L_;
    const size_t woff = (size_t)(n * B_ + b) * DK_ * D_;

    const float* Wg[3] = { Wq + woff, Wk + woff, Wv + woff };
    float (*Og[3])[L_] = { Qs, Ks, Vs };

    // ---- QKV projections: O = W (16x128) @ x_b (128x512) ----
    for (int m3 = 0; m3 < 3; ++m3) {
        const float* W = Wg[m3];
        for (int i = t; i < DK_ * D_; i += 256) ((float*)Ws)[i] = W[i];
        __syncthreads();

        float acc0[DK_], acc1[DK_];
        #pragma unroll
        for (int k = 0; k < DK_; ++k) { acc0[k] = 0.f; acc1[k] = 0.f; }

        for (int d = 0; d < D_; d += 4) {
            float xv0[4], xv1[4];
            #pragma unroll
            for (int j = 0; j < 4; ++j) {
                xv0[j] = xb[(size_t)(d + j) * L_ + t];
                xv1[j] = xb[(size_t)(d + j) * L_ + t + 256];
            }
            #pragma unroll
            for (int k = 0; k < DK_; ++k) {
                const float4 w = *(const float4*)&Ws[k][d];
                acc0[k] += w.x * xv0[0] + w.y * xv0[1] + w.z * xv0[2] + w.w * xv0[3];
                acc1[k] += w.x * xv1[0] + w.y * xv1[1] + w.z * xv1[2] + w.w * xv1[3];
            }
        }
        float (*O)[L_] = Og[m3];
        #pragma unroll
        for (int k = 0; k < DK_; ++k) {
            O[k][t]       = acc0[k];
            O[k][t + 256] = acc1[k];
        }
        __syncthreads();   // protect Ws before next matrix overwrites it
    }

    // ---- attention: for output column m, softmax over l of Q[:,l]·K[:,m]/4,
    //      then heads[:,m] = sum_l S[l,m] * V[:,l]. Each thread: m = t, t+256.
    float kr0[DK_], kr1[DK_];
    #pragma unroll
    for (int k = 0; k < DK_; ++k) { kr0[k] = Ks[k][t]; kr1[k] = Ks[k][t + 256]; }

    // pass 1: raw max over l (scale is positive -> commutes with max)
    float mx0 = -1e30f, mx1 = -1e30f;
    for (int l = 0; l < L_; l += 4) {
        float s0[4] = {0.f,0.f,0.f,0.f}, s1[4] = {0.f,0.f,0.f,0.f};
        #pragma unroll
        for (int k = 0; k < DK_; ++k) {
            const float4 q = *(const float4*)&Qs[k][l];
            s0[0] += q.x * kr0[k]; s0[1] += q.y * kr0[k];
            s0[2] += q.z * kr0[k]; s0[3] += q.w * kr0[k];
            s1[0] += q.x * kr1[k]; s1[1] += q.y * kr1[k];
            s1[2] += q.z * kr1[k]; s1[3] += q.w * kr1[k];
        }
        #pragma unroll
        for (int j = 0; j < 4; ++j) {
            mx0 = fmaxf(mx0, s0[j]);
            mx1 = fmaxf(mx1, s1[j]);
        }
    }
    const float base0 = mx0 * 0.25f;
    const float base1 = mx1 * 0.25f;

    // pass 2: exp + PV accumulate
    float Z0 = 0.f, Z1 = 0.f;
    float a0[DK_], a1[DK_];
    #pragma unroll
    for (int v = 0; v < DK_; ++v) { a0[v] = 0.f; a1[v] = 0.f; }

    for (int l = 0; l < L_; l += 4) {
        float s0[4] = {0.f,0.f,0.f,0.f}, s1[4] = {0.f,0.f,0.f,0.f};
        #pragma unroll
        for (int k = 0; k < DK_; ++k) {
            const float4 q = *(const float4*)&Qs[k][l];
            s0[0] += q.x * kr0[k]; s0[1] += q.y * kr0[k];
            s0[2] += q.z * kr0[k]; s0[3] += q.w * kr0[k];
            s1[0] += q.x * kr1[k]; s1[1] += q.y * kr1[k];
            s1[2] += q.z * kr1[k]; s1[3] += q.w * kr1[k];
        }
        float e0[4], e1[4];
        #pragma unroll
        for (int j = 0; j < 4; ++j) {
            e0[j] = __expf(s0[j] * 0.25f - base0);
            e1[j] = __expf(s1[j] * 0.25f - base1);
        }
        Z0 += e0[0] + e0[1] + e0[2] + e0[3];
        Z1 += e1[0] + e1[1] + e1[2] + e1[3];
        #pragma unroll
        for (int v = 0; v < DK_; ++v) {
            const float4 vv = *(const float4*)&Vs[v][l];
            a0[v] += vv.x * e0[0] + vv.y * e0[1] + vv.z * e0[2] + vv.w * e0[3];
            a1[v] += vv.x * e1[0] + vv.y * e1[1] + vv.z * e1[2] + vv.w * e1[3];
        }
    }
    const float rZ0 = 1.f / Z0, rZ1 = 1.f / Z1;

    // heads[::-1] head reversal: head n lands at row block (NH-1-n)*16
    float* hb = heads + (size_t)b * D_ * L_ + (size_t)(NH_ - 1 - n) * DK_ * L_;
    #pragma unroll
    for (int v = 0; v < DK_; ++v) {
        hb[(size_t)v * L_ + t]       = a0[v] * rZ0;
        hb[(size_t)v * L_ + t + 256] = a1[v] * rZ1;
    }
}

// ---------------------------------------------------------------------------
// Kernel B: out[b] = Wo[b] (128x128) @ heads[b] (128x512), per (b, col-tile).
// ---------------------------------------------------------------------------
__global__ __launch_bounds__(256) void out_proj(
    const float* __restrict__ Wo,     // [B][128][128]
    const float* __restrict__ heads,  // [B][128][512]
    float* __restrict__ out)          // [B][128][512]
{
    __shared__ __attribute__((aligned(16))) float Ws[D_ * D_];  // 64 KB
    __shared__ __attribute__((aligned(16))) float Hs[D_ * D_];  // 64 KB (128x128 tile)

    const int ct   = blockIdx.x;   // 0..3 column tile (128 cols each)
    const int b    = blockIdx.y;
    const int t    = threadIdx.x;
    const int col0 = ct * 128;

    const float* Wg = Wo + (size_t)b * D_ * D_;
    const float* Hg = heads + (size_t)b * D_ * L_;

    for (int i = t; i < D_ * D_; i += 256) {
        Ws[i] = Wg[i];
        const int d = i >> 7, c = i & 127;
        Hs[i] = Hg[(size_t)d * L_ + col0 + c];
    }
    __syncthreads();

    const int c  = t & 63;
    const int rg = t >> 6;   // wave id -> rows rg*32 .. rg*32+31

    float acc0[32], acc1[32];
    #pragma unroll
    for (int r = 0; r < 32; ++r) { acc0[r] = 0.f; acc1[r] = 0.f; }

    for (int d = 0; d < D_; d += 4) {
        float h0[4], h1[4];
        #pragma unroll
        for (int j = 0; j < 4; ++j) {
            h0[j] = Hs[(d + j) * 128 + c];
            h1[j] = Hs[(d + j) * 128 + c + 64];
        }
        #pragma unroll
        for (int r = 0; r < 32; ++r) {
            const float4 w = *(const float4*)&Ws[(rg * 32 + r) * 128 + d];
            acc0[r] += w.x * h0[0] + w.y * h0[1] + w.z * h0[2] + w.w * h0[3];
            acc1[r] += w.x * h1[0] + w.y * h1[1] + w.z * h1[2] + w.w * h1[3];
        }
    }

    float* ob = out + (size_t)b * D_ * L_;
    #pragma unroll
    for (int r = 0; r < 32; ++r) {
        ob[(size_t)(rg * 32 + r) * L_ + col0 + c]      = acc0[r];
        ob[(size_t)(rg * 32 + r) * L_ + col0 + c + 64] = acc1[r];
    }
}

extern "C" void kernel_launch(void* const* d_in, const int* in_sizes, int n_in,
                              void* d_out, int out_size, void* d_ws, size_t ws_size,
                              hipStream_t stream)
{
    const float* x  = (const float*)d_in[0];
    const float* Wq = (const float*)d_in[1];
    const float* Wk = (const float*)d_in[2];
    const float* Wv = (const float*)d_in[3];
    const float* Wo = (const float*)d_in[4];
    float* out = (float*)d_out;

    // heads scratch: B * 128 * 512 floats = 8 MB
    float* heads = (float*)d_ws;

    attn_fused<<<dim3(NH_ * B_), dim3(256), 0, stream>>>(x, Wq, Wk, Wv, heads);
    out_proj<<<dim3(4, B_), dim3(256), 0, stream>>>(Wo, heads, out);
}

// Round 2
// 86.963 us; speedup vs baseline: 3.4330x; 3.4330x over previous
//
#include <hip/hip_runtime.h>
#include <hip/hip_bf16.h>
#include <math.h>

#define B_   32
#define D_   128
#define L_   512
#define NH_  8
#define DK_  16

#define QKS  24    // Qt/Kt row stride in bf16 elems ([512][16] + pad 8)
#define VST  520   // V row stride ([16][512] + pad 8)
#define SST  40    // S row stride ([64][32] + pad 8), per-wave

typedef __attribute__((ext_vector_type(8))) short  bf16x8;
typedef __attribute__((ext_vector_type(4))) float  f32x4;
typedef __attribute__((ext_vector_type(4))) unsigned short u16x4;

__device__ __forceinline__ unsigned short f2bf(float f) {
    __hip_bfloat16 h = __float2bfloat16(f);          // RNE
    return __builtin_bit_cast(unsigned short, h);
}
__device__ __forceinline__ float bf2f(unsigned short u) {
    __hip_bfloat16 h = __builtin_bit_cast(__hip_bfloat16, u);
    return __bfloat162float(h);
}

#define MFMA16(a, b, c) __builtin_amdgcn_mfma_f32_16x16x32_bf16((a), (b), (c), 0, 0, 0)

// ---------------------------------------------------------------------------
// Fused per-(head,batch) attention with bf16x3 MFMA + flash online softmax.
// grid 256 = (n,b), 512 threads = 8 waves. Wave w owns m-span [64w, 64w+64).
// ---------------------------------------------------------------------------
__global__ __launch_bounds__(512) void attn_mfma(
    const float* __restrict__ x,    // [B][D][L]
    const float* __restrict__ Wq,   // [NH][B][DK][D]
    const float* __restrict__ Wk,
    const float* __restrict__ Wv,
    float* __restrict__ heads)      // [B][NH*DK][L] (head-reversed)
{
    __shared__ __attribute__((aligned(16))) unsigned short Qh[512 * QKS];
    __shared__ __attribute__((aligned(16))) unsigned short Ql[512 * QKS];
    __shared__ __attribute__((aligned(16))) unsigned short Kh[512 * QKS];
    __shared__ __attribute__((aligned(16))) unsigned short Kl[512 * QKS];
    __shared__ __attribute__((aligned(16))) unsigned short Vs[16 * VST];
    __shared__ __attribute__((aligned(16))) unsigned short Sl[8][64 * SST];

    const int nb = blockIdx.x;
    const int n  = nb >> 5;
    const int b  = nb & 31;
    const int t  = threadIdx.x;
    const int wv = t >> 6;          // wave 0..7
    const int ln = t & 63;
    const int l16 = ln & 15;        // 16x16-frag row/col within tile
    const int g4  = ln >> 4;        // 0..3

    const float* xb = x + (size_t)b * D_ * L_;
    const size_t woff = (size_t)(n * B_ + b) * DK_ * D_;
    const float* pWq = Wq + woff;
    const float* pWk = Wk + woff;
    const float* pWv = Wv + woff;

    // ================= P1: Q,K,V = W @ x  (MFMA, bf16x3 for Q,K) =========
    f32x4 Qa[4], Ka[4], Va[4];
    #pragma unroll
    for (int lt = 0; lt < 4; ++lt) {
        Qa[lt] = (f32x4){0.f,0.f,0.f,0.f};
        Ka[lt] = (f32x4){0.f,0.f,0.f,0.f};
        Va[lt] = (f32x4){0.f,0.f,0.f,0.f};
    }

    for (int ks = 0; ks < 4; ++ks) {
        const int d0 = ks * 32 + g4 * 8;       // 8 consecutive d per lane
        bf16x8 aqh, aql, akh, akl, avh;
        #pragma unroll
        for (int j = 0; j < 8; ++j) {
            float wq = pWq[l16 * D_ + d0 + j];
            unsigned short h = f2bf(wq);
            aqh[j] = (short)h; aql[j] = (short)f2bf(wq - bf2f(h));
            float wk = pWk[l16 * D_ + d0 + j];
            h = f2bf(wk);
            akh[j] = (short)h; akl[j] = (short)f2bf(wk - bf2f(h));
            avh[j] = (short)f2bf(pWv[l16 * D_ + d0 + j]);
        }
        for (int lt = 0; lt < 4; ++lt) {
            const int l = wv * 64 + lt * 16 + l16;
            bf16x8 bxh, bxl;
            #pragma unroll
            for (int j = 0; j < 8; ++j) {
                float xv = xb[(size_t)(d0 + j) * L_ + l];
                unsigned short h = f2bf(xv);
                bxh[j] = (short)h; bxl[j] = (short)f2bf(xv - bf2f(h));
            }
            Qa[lt] = MFMA16(aqh, bxh, Qa[lt]);
            Qa[lt] = MFMA16(aqh, bxl, Qa[lt]);
            Qa[lt] = MFMA16(aql, bxh, Qa[lt]);
            Ka[lt] = MFMA16(akh, bxh, Ka[lt]);
            Ka[lt] = MFMA16(akh, bxl, Ka[lt]);
            Ka[lt] = MFMA16(akl, bxh, Ka[lt]);
            Va[lt] = MFMA16(avh, bxh, Va[lt]);
        }
    }

    // write transposed hi/lo to LDS. D-frag: col l = l16, row k = 4*g4+r.
    #pragma unroll
    for (int lt = 0; lt < 4; ++lt) {
        const int l = wv * 64 + lt * 16 + l16;
        u16x4 qh4, ql4, kh4, kl4;
        #pragma unroll
        for (int r = 0; r < 4; ++r) {
            float q = Qa[lt][r] * 0.25f;           // fold 1/sqrt(dk)
            unsigned short h = f2bf(q);
            qh4[r] = h; ql4[r] = f2bf(q - bf2f(h));
            float kv = Ka[lt][r];
            h = f2bf(kv);
            kh4[r] = h; kl4[r] = f2bf(kv - bf2f(h));
            Vs[(g4 * 4 + r) * VST + l] = f2bf(Va[lt][r]);
        }
        *(u16x4*)&Qh[l * QKS + g4 * 4] = qh4;
        *(u16x4*)&Ql[l * QKS + g4 * 4] = ql4;
        *(u16x4*)&Kh[l * QKS + g4 * 4] = kh4;
        *(u16x4*)&Kl[l * QKS + g4 * 4] = kl4;
    }
    __syncthreads();

    // ================= P2: flash attention over l-tiles of 32 =============
    f32x4 pv[4];
    float rmax[4], Zs[4];
    #pragma unroll
    for (int mt = 0; mt < 4; ++mt) {
        pv[mt] = (f32x4){0.f,0.f,0.f,0.f};
        rmax[mt] = -3.0e38f; Zs[mt] = 0.f;
    }
    const bool kact = (g4 < 2);        // K-dim 16, padded to 32 with zeros
    const bf16x8 z8 = {0,0,0,0,0,0,0,0};
    unsigned short* mySl = &Sl[wv][0];

    for (int t32 = 0; t32 < 16; ++t32) {
        const int lb = t32 * 32;
        // A-frags: Qt rows = l-tile, two i-tiles of 16
        bf16x8 ah0 = z8, al0 = z8, ah1 = z8, al1 = z8;
        if (kact) {
            int i0 = (lb + l16) * QKS + g4 * 8;
            int i1 = (lb + 16 + l16) * QKS + g4 * 8;
            ah0 = *(const bf16x8*)&Qh[i0]; al0 = *(const bf16x8*)&Ql[i0];
            ah1 = *(const bf16x8*)&Qh[i1]; al1 = *(const bf16x8*)&Ql[i1];
        }
        #pragma unroll
        for (int mt = 0; mt < 4; ++mt) {
            const int mrow = wv * 64 + mt * 16 + l16;
            bf16x8 bh = z8, bl = z8;
            if (kact) {
                int ib = mrow * QKS + g4 * 8;
                bh = *(const bf16x8*)&Kh[ib]; bl = *(const bf16x8*)&Kl[ib];
            }
            f32x4 s0 = (f32x4){0.f,0.f,0.f,0.f};
            f32x4 s1 = (f32x4){0.f,0.f,0.f,0.f};
            s0 = MFMA16(ah0, bh, s0); s0 = MFMA16(ah0, bl, s0); s0 = MFMA16(al0, bh, s0);
            s1 = MFMA16(ah1, bh, s1); s1 = MFMA16(ah1, bl, s1); s1 = MFMA16(al1, bh, s1);

            // softmax over l: tile max (rows = l)
            float mx = fmaxf(fmaxf(fmaxf(s0[0], s0[1]), fmaxf(s0[2], s0[3])),
                             fmaxf(fmaxf(s1[0], s1[1]), fmaxf(s1[2], s1[3])));
            mx = fmaxf(mx, __shfl_xor(mx, 16));
            mx = fmaxf(mx, __shfl_xor(mx, 32));
            float nm = fmaxf(rmax[mt], mx);
            float fr = __expf(rmax[mt] - nm);
            rmax[mt] = nm;

            float p0[4], p1[4], ps = 0.f;
            #pragma unroll
            for (int r = 0; r < 4; ++r) { p0[r] = __expf(s0[r] - nm); ps += p0[r]; }
            #pragma unroll
            for (int r = 0; r < 4; ++r) { p1[r] = __expf(s1[r] - nm); ps += p1[r]; }
            ps += __shfl_xor(ps, 16);
            ps += __shfl_xor(ps, 32);
            Zs[mt] = Zs[mt] * fr + ps;
            pv[mt] *= fr;

            u16x4 pb0, pb1;
            #pragma unroll
            for (int r = 0; r < 4; ++r) { pb0[r] = f2bf(p0[r]); pb1[r] = f2bf(p1[r]); }
            // l_local = it*16 + 4*g4 + r
            *(u16x4*)&mySl[(mt * 16 + l16) * SST + g4 * 4]      = pb0;
            *(u16x4*)&mySl[(mt * 16 + l16) * SST + 16 + g4 * 4] = pb1;
        }
        // wave-private S: fence cross-lane LDS write->read (compiler can't see it)
        asm volatile("s_waitcnt lgkmcnt(0)" ::: "memory");
        // PV: A = V[v][lb..lb+31], B = S[l_local][m]
        bf16x8 aV = *(const bf16x8*)&Vs[l16 * VST + lb + g4 * 8];
        #pragma unroll
        for (int mt = 0; mt < 4; ++mt) {
            bf16x8 bS = *(const bf16x8*)&mySl[(mt * 16 + l16) * SST + g4 * 8];
            pv[mt] = MFMA16(aV, bS, pv[mt]);
        }
    }

    // epilogue: normalize, write heads (head-reversed)
    float* hb = heads + (size_t)b * D_ * L_ + (size_t)(NH_ - 1 - n) * DK_ * L_;
    #pragma unroll
    for (int mt = 0; mt < 4; ++mt) {
        float rz = 1.f / Zs[mt];
        const int m = wv * 64 + mt * 16 + l16;
        #pragma unroll
        for (int r = 0; r < 4; ++r) {
            hb[(size_t)(g4 * 4 + r) * L_ + m] = pv[mt][r] * rz;
        }
    }
}

// ---------------------------------------------------------------------------
// Kernel B: out[b] = Wo[b] (128x128) @ heads[b] (128x512)  (unchanged, fp32)
// ---------------------------------------------------------------------------
__global__ __launch_bounds__(256) void out_proj(
    const float* __restrict__ Wo,     // [B][128][128]
    const float* __restrict__ heads,  // [B][128][512]
    float* __restrict__ out)          // [B][128][512]
{
    __shared__ __attribute__((aligned(16))) float Ws[D_ * D_];
    __shared__ __attribute__((aligned(16))) float Hs[D_ * D_];

    const int ct   = blockIdx.x;
    const int b    = blockIdx.y;
    const int t    = threadIdx.x;
    const int col0 = ct * 128;

    const float* Wg = Wo + (size_t)b * D_ * D_;
    const float* Hg = heads + (size_t)b * D_ * L_;

    for (int i = t; i < D_ * D_; i += 256) {
        Ws[i] = Wg[i];
        const int d = i >> 7, c = i & 127;
        Hs[i] = Hg[(size_t)d * L_ + col0 + c];
    }
    __syncthreads();

    const int c  = t & 63;
    const int rg = t >> 6;

    float acc0[32], acc1[32];
    #pragma unroll
    for (int r = 0; r < 32; ++r) { acc0[r] = 0.f; acc1[r] = 0.f; }

    for (int d = 0; d < D_; d += 4) {
        float h0[4], h1[4];
        #pragma unroll
        for (int j = 0; j < 4; ++j) {
            h0[j] = Hs[(d + j) * 128 + c];
            h1[j] = Hs[(d + j) * 128 + c + 64];
        }
        #pragma unroll
        for (int r = 0; r < 32; ++r) {
            const float4 w = *(const float4*)&Ws[(rg * 32 + r) * 128 + d];
            acc0[r] += w.x * h0[0] + w.y * h0[1] + w.z * h0[2] + w.w * h0[3];
            acc1[r] += w.x * h1[0] + w.y * h1[1] + w.z * h1[2] + w.w * h1[3];
        }
    }

    float* ob = out + (size_t)b * D_ * L_;
    #pragma unroll
    for (int r = 0; r < 32; ++r) {
        ob[(size_t)(rg * 32 + r) * L_ + col0 + c]      = acc0[r];
        ob[(size_t)(rg * 32 + r) * L_ + col0 + c + 64] = acc1[r];
    }
}

extern "C" void kernel_launch(void* const* d_in, const int* in_sizes, int n_in,
                              void* d_out, int out_size, void* d_ws, size_t ws_size,
                              hipStream_t stream)
{
    const float* x  = (const float*)d_in[0];
    const float* Wq = (const float*)d_in[1];
    const float* Wk = (const float*)d_in[2];
    const float* Wv = (const float*)d_in[3];
    const float* Wo = (const float*)d_in[4];
    float* out = (float*)d_out;

    float* heads = (float*)d_ws;   // B*128*512 floats = 8 MB

    attn_mfma<<<dim3(NH_ * B_), dim3(512), 0, stream>>>(x, Wq, Wk, Wv, heads);
    out_proj<<<dim3(4, B_), dim3(256), 0, stream>>>(Wo, heads, out);
}

// Round 3
// 59.069 us; speedup vs baseline: 5.0542x; 1.4722x over previous
//
#include <hip/hip_runtime.h>
#include <hip/hip_bf16.h>
#include <math.h>

#define B_   32
#define D_   128
#define L_   512
#define NH_  8
#define DK_  16

#define QKS  24    // Qt/Kt row stride in bf16 elems ([512][16] + pad 8)
#define VST  520   // V row stride ([16][512] + pad 8)
#define SST  40    // S row stride ([64][32] + pad 8), per-wave

typedef __attribute__((ext_vector_type(8))) short  bf16x8;
typedef __attribute__((ext_vector_type(4))) float  f32x4;
typedef __attribute__((ext_vector_type(4))) unsigned short u16x4;

__device__ __forceinline__ unsigned short f2bf(float f) {
    __hip_bfloat16 h = __float2bfloat16(f);          // RNE
    return __builtin_bit_cast(unsigned short, h);
}
__device__ __forceinline__ float bf2f(unsigned short u) {
    __hip_bfloat16 h = __builtin_bit_cast(__hip_bfloat16, u);
    return __bfloat162float(h);
}

#define MFMA16(a, b, c) __builtin_amdgcn_mfma_f32_16x16x32_bf16((a), (b), (c), 0, 0, 0)

// ---------------------------------------------------------------------------
// Kernel A: fused per-(head,batch) attention, bf16x3 MFMA + flash softmax.
// Epilogue writes heads TRANSPOSED as hi/lo bf16 planes: Ht[b][n=512][k=128],
// head-reversed in k, so out_proj B-frags are contiguous 16B loads.
// ---------------------------------------------------------------------------
__global__ __launch_bounds__(512) void attn_mfma(
    const float* __restrict__ x,    // [B][D][L]
    const float* __restrict__ Wq,   // [NH][B][DK][D]
    const float* __restrict__ Wk,
    const float* __restrict__ Wv,
    unsigned short* __restrict__ Hh,  // [B][512][128] bf16 hi (transposed heads)
    unsigned short* __restrict__ Hl)  // [B][512][128] bf16 lo
{
    __shared__ __attribute__((aligned(16))) unsigned short Qh[512 * QKS];
    __shared__ __attribute__((aligned(16))) unsigned short Ql[512 * QKS];
    __shared__ __attribute__((aligned(16))) unsigned short Kh[512 * QKS];
    __shared__ __attribute__((aligned(16))) unsigned short Kl[512 * QKS];
    __shared__ __attribute__((aligned(16))) unsigned short Vs[16 * VST];
    __shared__ __attribute__((aligned(16))) unsigned short Sl[8][64 * SST];

    const int nb = blockIdx.x;
    const int n  = nb >> 5;
    const int b  = nb & 31;
    const int t  = threadIdx.x;
    const int wv = t >> 6;          // wave 0..7
    const int ln = t & 63;
    const int l16 = ln & 15;
    const int g4  = ln >> 4;

    const float* xb = x + (size_t)b * D_ * L_;
    const size_t woff = (size_t)(n * B_ + b) * DK_ * D_;
    const float* pWq = Wq + woff;
    const float* pWk = Wk + woff;
    const float* pWv = Wv + woff;

    // ================= P1: Q,K,V = W @ x  (MFMA, bf16x3 for Q,K) =========
    f32x4 Qa[4], Ka[4], Va[4];
    #pragma unroll
    for (int lt = 0; lt < 4; ++lt) {
        Qa[lt] = (f32x4){0.f,0.f,0.f,0.f};
        Ka[lt] = (f32x4){0.f,0.f,0.f,0.f};
        Va[lt] = (f32x4){0.f,0.f,0.f,0.f};
    }

    for (int ks = 0; ks < 4; ++ks) {
        const int d0 = ks * 32 + g4 * 8;
        bf16x8 aqh, aql, akh, akl, avh;
        #pragma unroll
        for (int j = 0; j < 8; ++j) {
            float wq = pWq[l16 * D_ + d0 + j];
            unsigned short h = f2bf(wq);
            aqh[j] = (short)h; aql[j] = (short)f2bf(wq - bf2f(h));
            float wk = pWk[l16 * D_ + d0 + j];
            h = f2bf(wk);
            akh[j] = (short)h; akl[j] = (short)f2bf(wk - bf2f(h));
            avh[j] = (short)f2bf(pWv[l16 * D_ + d0 + j]);
        }
        for (int lt = 0; lt < 4; ++lt) {
            const int l = wv * 64 + lt * 16 + l16;
            bf16x8 bxh, bxl;
            #pragma unroll
            for (int j = 0; j < 8; ++j) {
                float xv = xb[(size_t)(d0 + j) * L_ + l];
                unsigned short h = f2bf(xv);
                bxh[j] = (short)h; bxl[j] = (short)f2bf(xv - bf2f(h));
            }
            Qa[lt] = MFMA16(aqh, bxh, Qa[lt]);
            Qa[lt] = MFMA16(aqh, bxl, Qa[lt]);
            Qa[lt] = MFMA16(aql, bxh, Qa[lt]);
            Ka[lt] = MFMA16(akh, bxh, Ka[lt]);
            Ka[lt] = MFMA16(akh, bxl, Ka[lt]);
            Ka[lt] = MFMA16(akl, bxh, Ka[lt]);
            Va[lt] = MFMA16(avh, bxh, Va[lt]);
        }
    }

    #pragma unroll
    for (int lt = 0; lt < 4; ++lt) {
        const int l = wv * 64 + lt * 16 + l16;
        u16x4 qh4, ql4, kh4, kl4;
        #pragma unroll
        for (int r = 0; r < 4; ++r) {
            float q = Qa[lt][r] * 0.25f;           // fold 1/sqrt(dk)
            unsigned short h = f2bf(q);
            qh4[r] = h; ql4[r] = f2bf(q - bf2f(h));
            float kv = Ka[lt][r];
            h = f2bf(kv);
            kh4[r] = h; kl4[r] = f2bf(kv - bf2f(h));
            Vs[(g4 * 4 + r) * VST + l] = f2bf(Va[lt][r]);
        }
        *(u16x4*)&Qh[l * QKS + g4 * 4] = qh4;
        *(u16x4*)&Ql[l * QKS + g4 * 4] = ql4;
        *(u16x4*)&Kh[l * QKS + g4 * 4] = kh4;
        *(u16x4*)&Kl[l * QKS + g4 * 4] = kl4;
    }
    __syncthreads();

    // ================= P2: flash attention over l-tiles of 32 =============
    f32x4 pv[4];
    float rmax[4], Zs[4];
    #pragma unroll
    for (int mt = 0; mt < 4; ++mt) {
        pv[mt] = (f32x4){0.f,0.f,0.f,0.f};
        rmax[mt] = -3.0e38f; Zs[mt] = 0.f;
    }
    const bool kact = (g4 < 2);
    const bf16x8 z8 = {0,0,0,0,0,0,0,0};
    unsigned short* mySl = &Sl[wv][0];

    for (int t32 = 0; t32 < 16; ++t32) {
        const int lb = t32 * 32;
        bf16x8 ah0 = z8, al0 = z8, ah1 = z8, al1 = z8;
        if (kact) {
            int i0 = (lb + l16) * QKS + g4 * 8;
            int i1 = (lb + 16 + l16) * QKS + g4 * 8;
            ah0 = *(const bf16x8*)&Qh[i0]; al0 = *(const bf16x8*)&Ql[i0];
            ah1 = *(const bf16x8*)&Qh[i1]; al1 = *(const bf16x8*)&Ql[i1];
        }
        #pragma unroll
        for (int mt = 0; mt < 4; ++mt) {
            const int mrow = wv * 64 + mt * 16 + l16;
            bf16x8 bh = z8, bl = z8;
            if (kact) {
                int ib = mrow * QKS + g4 * 8;
                bh = *(const bf16x8*)&Kh[ib]; bl = *(const bf16x8*)&Kl[ib];
            }
            f32x4 s0 = (f32x4){0.f,0.f,0.f,0.f};
            f32x4 s1 = (f32x4){0.f,0.f,0.f,0.f};
            s0 = MFMA16(ah0, bh, s0); s0 = MFMA16(ah0, bl, s0); s0 = MFMA16(al0, bh, s0);
            s1 = MFMA16(ah1, bh, s1); s1 = MFMA16(ah1, bl, s1); s1 = MFMA16(al1, bh, s1);

            float mx = fmaxf(fmaxf(fmaxf(s0[0], s0[1]), fmaxf(s0[2], s0[3])),
                             fmaxf(fmaxf(s1[0], s1[1]), fmaxf(s1[2], s1[3])));
            mx = fmaxf(mx, __shfl_xor(mx, 16));
            mx = fmaxf(mx, __shfl_xor(mx, 32));
            float nm = fmaxf(rmax[mt], mx);
            float fr = __expf(rmax[mt] - nm);
            rmax[mt] = nm;

            float p0[4], p1[4], ps = 0.f;
            #pragma unroll
            for (int r = 0; r < 4; ++r) { p0[r] = __expf(s0[r] - nm); ps += p0[r]; }
            #pragma unroll
            for (int r = 0; r < 4; ++r) { p1[r] = __expf(s1[r] - nm); ps += p1[r]; }
            ps += __shfl_xor(ps, 16);
            ps += __shfl_xor(ps, 32);
            Zs[mt] = Zs[mt] * fr + ps;
            pv[mt] *= fr;

            u16x4 pb0, pb1;
            #pragma unroll
            for (int r = 0; r < 4; ++r) { pb0[r] = f2bf(p0[r]); pb1[r] = f2bf(p1[r]); }
            *(u16x4*)&mySl[(mt * 16 + l16) * SST + g4 * 4]      = pb0;
            *(u16x4*)&mySl[(mt * 16 + l16) * SST + 16 + g4 * 4] = pb1;
        }
        asm volatile("s_waitcnt lgkmcnt(0)" ::: "memory");
        bf16x8 aV = *(const bf16x8*)&Vs[l16 * VST + lb + g4 * 8];
        #pragma unroll
        for (int mt = 0; mt < 4; ++mt) {
            bf16x8 bS = *(const bf16x8*)&mySl[(mt * 16 + l16) * SST + g4 * 8];
            pv[mt] = MFMA16(aV, bS, pv[mt]);
        }
    }

    // epilogue: normalize, split hi/lo, write TRANSPOSED + head-reversed:
    // Ht[b][n = m][k = (NH-1-n_head)*16 + g4*4 + r]
    const size_t hbase = (size_t)b * 512 * 128 + (size_t)(NH_ - 1 - n) * 16 + g4 * 4;
    #pragma unroll
    for (int mt = 0; mt < 4; ++mt) {
        float rz = 1.f / Zs[mt];
        const int m = wv * 64 + mt * 16 + l16;
        u16x4 h4, l4;
        #pragma unroll
        for (int r = 0; r < 4; ++r) {
            float v = pv[mt][r] * rz;
            unsigned short h = f2bf(v);
            h4[r] = h; l4[r] = f2bf(v - bf2f(h));
        }
        const size_t off = hbase + (size_t)m * 128;
        *(u16x4*)&Hh[off] = h4;
        *(u16x4*)&Hl[off] = l4;
    }
}

// ---------------------------------------------------------------------------
// Kernel B: out[b] = Wo[b] (128x128) @ heads[b] (128x512), bf16x3 MFMA,
// pure-register (no LDS, no syncthreads). grid (8 col-tiles, 32 b), 512 thr.
// Wave w owns m-tile w (16 rows) x 64 cols.
// ---------------------------------------------------------------------------
__global__ __launch_bounds__(512) void out_proj_mfma(
    const float* __restrict__ Wo,           // [B][128][128]
    const unsigned short* __restrict__ Hh,  // [B][512][128] hi
    const unsigned short* __restrict__ Hl,  // lo
    float* __restrict__ out)                // [B][128][512]
{
    const int ct = blockIdx.x;     // 0..7 -> col0 = ct*64
    const int b  = blockIdx.y;
    const int t  = threadIdx.x;
    const int wv = t >> 6;         // m-tile 0..7
    const int ln = t & 63;
    const int l16 = ln & 15;
    const int g4  = ln >> 4;

    const float* Wb = Wo + (size_t)b * D_ * D_;
    const unsigned short* Hhb = Hh + (size_t)b * 512 * 128;
    const unsigned short* Hlb = Hl + (size_t)b * 512 * 128;

    f32x4 acc[4];
    #pragma unroll
    for (int nt = 0; nt < 4; ++nt) acc[nt] = (f32x4){0.f,0.f,0.f,0.f};

    #pragma unroll
    for (int ks = 0; ks < 4; ++ks) {
        const int k0 = ks * 32 + g4 * 8;
        // A-frag: row m = wv*16 + l16, k = k0..k0+7 (fp32 -> hi/lo)
        const float* ap = Wb + (size_t)(wv * 16 + l16) * D_ + k0;
        const float4 w0 = *(const float4*)ap;
        const float4 w1 = *(const float4*)(ap + 4);
        bf16x8 Ah, Al;
        {
            const float wf[8] = {w0.x,w0.y,w0.z,w0.w,w1.x,w1.y,w1.z,w1.w};
            #pragma unroll
            for (int j = 0; j < 8; ++j) {
                unsigned short h = f2bf(wf[j]);
                Ah[j] = (short)h; Al[j] = (short)f2bf(wf[j] - bf2f(h));
            }
        }
        #pragma unroll
        for (int nt = 0; nt < 4; ++nt) {
            const size_t boff = (size_t)(ct * 64 + nt * 16 + l16) * 128 + k0;
            bf16x8 Bh = *(const bf16x8*)&Hhb[boff];
            bf16x8 Bl = *(const bf16x8*)&Hlb[boff];
            acc[nt] = MFMA16(Ah, Bh, acc[nt]);
            acc[nt] = MFMA16(Ah, Bl, acc[nt]);
            acc[nt] = MFMA16(Al, Bh, acc[nt]);
        }
    }

    // C-frag: row = wv*16 + g4*4 + r, col = ct*64 + nt*16 + l16
    float* ob = out + (size_t)b * D_ * L_;
    #pragma unroll
    for (int nt = 0; nt < 4; ++nt) {
        #pragma unroll
        for (int r = 0; r < 4; ++r) {
            ob[(size_t)(wv * 16 + g4 * 4 + r) * L_ + ct * 64 + nt * 16 + l16] = acc[nt][r];
        }
    }
}

extern "C" void kernel_launch(void* const* d_in, const int* in_sizes, int n_in,
                              void* d_out, int out_size, void* d_ws, size_t ws_size,
                              hipStream_t stream)
{
    const float* x  = (const float*)d_in[0];
    const float* Wq = (const float*)d_in[1];
    const float* Wk = (const float*)d_in[2];
    const float* Wv = (const float*)d_in[3];
    const float* Wo = (const float*)d_in[4];
    float* out = (float*)d_out;

    unsigned short* Hh = (unsigned short*)d_ws;              // 4 MB
    unsigned short* Hl = Hh + (size_t)B_ * 512 * 128;        // 4 MB

    attn_mfma<<<dim3(NH_ * B_), dim3(512), 0, stream>>>(x, Wq, Wk, Wv, Hh, Hl);
    out_proj_mfma<<<dim3(8, B_), dim3(512), 0, stream>>>(Wo, Hh, Hl, out);
}